// Round 21
// baseline (152.146 us; speedup 1.0000x reference)
//
#include <hip/hip_runtime.h>

#define N_POINTS  500000
#define K_CENT    512
#define W_DIM     64
#define N_TILES   (N_POINTS / 32)              // 15625 exact 32-point tiles
#define TPB_TILES 62
#define N_BLOCKS  ((N_TILES + TPB_TILES - 1) / TPB_TILES)   // 253

typedef _Float16 half8 __attribute__((ext_vector_type(8)));
typedef _Float16 half4 __attribute__((ext_vector_type(4)));
typedef float    f32x4 __attribute__((ext_vector_type(4)));

// ---- pre-kernel 1 (R20 verbatim): codebook -> fragment-ordered f16 hi/lo of
// w=-2c. Layout [t:16][pl:2][cs:2][ks:2][lane:64][j:8]; cent c = t*32+cs*16+
// (l&15), dim d = ks*32+(l>>4)*8+j; lo = unscaled residual (REQUIRED, R19).
__global__ void cvt_kernel(const float* __restrict__ cb,
                           _Float16* __restrict__ cbf) {
    int id = blockIdx.x * 256 + threadIdx.x;           // 4096 ids
    if (id >= K_CENT * 8) return;
    int c = id >> 3, o = (id & 7) * 8;
    int t = c >> 5, csub = (c >> 4) & 1, r = c & 15;
    int kstep = o >> 5, grp = (o >> 3) & 3;
    int lane = grp * 16 + r;
    const float* src = cb + (size_t)c * W_DIM + o;
    half8 h, l;
#pragma unroll
    for (int j = 0; j < 8; ++j) {
        float w = -2.0f * src[j];
        _Float16 hh = (_Float16)w;                     // RNE
        h[j] = hh;
        l[j] = (_Float16)(w - (float)hh);
    }
    size_t bh = ((((size_t)t * 2 + 0) * 2 + csub) * 2 + kstep) * 512 + (size_t)lane * 8;
    size_t bl = ((((size_t)t * 2 + 1) * 2 + csub) * 2 + kstep) * 512 + (size_t)lane * 8;
    *(half8*)(cbf + bh) = h;
    *(half8*)(cbf + bl) = l;
}

// ---- pre-kernel 2 (R20 verbatim): c2 in double
__global__ void c2_kernel(const float* __restrict__ cb, float* __restrict__ c2) {
    int c = blockIdx.x * 256 + threadIdx.x;
    if (c >= K_CENT) return;
    const float4* row = (const float4*)(cb + (size_t)c * W_DIM);
    double s = 0.0;
#pragma unroll
    for (int j = 0; j < W_DIM / 4; ++j) {
        float4 v = row[j];
        s += (double)v.x * v.x + (double)v.y * v.y + (double)v.z * v.z + (double)v.w * v.w;
    }
    c2[c] = (float)s;
}

#define MFMA16(A, B, C) __builtin_amdgcn_mfma_f32_16x16x32_f16(A, B, C, 0, 0, 0)

// Stage tile T: 512 threads, one float4 each (coalesced 8KB), convert to
// hi/lo f16 and write B-fragments to Bbuf[T&1]; x2 (fp32, deterministic
// fixed-order) -> x2buf[T%3] (mod-3: staged 1 ahead, read 1 behind).
// B layout: [ps:2][pl:2][ks:2][lane:64][j:8] f16 (4 KB... x2 planes = 8KB).
#define STAGE(T)                                                               \
    {                                                                          \
        int p  = tid >> 4, dq = tid & 15, d = dq * 4;                          \
        const float4 f = *(const float4*)(X + ((size_t)(T) * 32 + p) * W_DIM + d); \
        half4 hi, lo;                                                          \
        hi[0] = (_Float16)f.x; lo[0] = (_Float16)(f.x - (float)hi[0]);         \
        hi[1] = (_Float16)f.y; lo[1] = (_Float16)(f.y - (float)hi[1]);         \
        hi[2] = (_Float16)f.z; lo[2] = (_Float16)(f.z - (float)hi[2]);         \
        hi[3] = (_Float16)f.w; lo[3] = (_Float16)(f.w - (float)hi[3]);         \
        float x2p = f.x * f.x + f.y * f.y + f.z * f.z + f.w * f.w;             \
        x2p += __shfl_xor(x2p, 1);                                             \
        x2p += __shfl_xor(x2p, 2);                                             \
        x2p += __shfl_xor(x2p, 4);                                             \
        x2p += __shfl_xor(x2p, 8);                                             \
        if (dq == 0) x2buf[(T) % 3][p] = x2p;                                  \
        int ps = p >> 4, lp = p & 15, ks = d >> 5, gd = (d >> 3) & 3, j0 = d & 7; \
        int ls = gd * 16 + lp;                                                 \
        *(half4*)&Bbuf[(T) & 1][((ps * 2 + 0) * 2 + ks) * 512 + ls * 8 + j0] = hi; \
        *(half4*)&Bbuf[(T) & 1][((ps * 2 + 1) * 2 + ks) * 512 + ls * 8 + j0] = lo; \
    }

// Compute tile T: read B-fragments (8 x ds_read_b128, conflict-free), 48
// MFMAs = 8 chains (c,cs,ps) x 6-deep 3-term, C-in = q (c2, in regs).
// Per-tile partial argmin over this wave's 64 cents -> part[T&1][wave].
#define COMPUTE(T)                                                             \
    {                                                                          \
        int buf_ = (T) & 1;                                                    \
        half8 bh[2][2], bl[2][2];                                              \
        _Pragma("unroll")                                                      \
        for (int ps = 0; ps < 2; ++ps)                                         \
            _Pragma("unroll")                                                  \
            for (int ks = 0; ks < 2; ++ks) {                                   \
                bh[ps][ks] = *(const half8*)&Bbuf[buf_][((ps * 2 + 0) * 2 + ks) * 512 + lane * 8]; \
                bl[ps][ks] = *(const half8*)&Bbuf[buf_][((ps * 2 + 1) * 2 + ks) * 512 + lane * 8]; \
            }                                                                  \
        f32x4 acc[2][2][2];                                                    \
        __builtin_amdgcn_s_setprio(1);                                         \
        _Pragma("unroll")                                                      \
        for (int c = 0; c < 2; ++c)                                            \
            _Pragma("unroll")                                                  \
            for (int cs = 0; cs < 2; ++cs)                                     \
                _Pragma("unroll")                                              \
                for (int ps = 0; ps < 2; ++ps)                                 \
                    acc[c][cs][ps] = MFMA16(aH[c][cs][0], bh[ps][0], q[c][cs]); \
        _Pragma("unroll")                                                      \
        for (int c = 0; c < 2; ++c)                                            \
            _Pragma("unroll")                                                  \
            for (int cs = 0; cs < 2; ++cs)                                     \
                _Pragma("unroll")                                              \
                for (int ps = 0; ps < 2; ++ps)                                 \
                    acc[c][cs][ps] = MFMA16(aH[c][cs][1], bh[ps][1], acc[c][cs][ps]); \
        _Pragma("unroll")                                                      \
        for (int c = 0; c < 2; ++c)                                            \
            _Pragma("unroll")                                                  \
            for (int cs = 0; cs < 2; ++cs)                                     \
                _Pragma("unroll")                                              \
                for (int ps = 0; ps < 2; ++ps)                                 \
                    acc[c][cs][ps] = MFMA16(aL[c][cs][0], bh[ps][0], acc[c][cs][ps]); \
        _Pragma("unroll")                                                      \
        for (int c = 0; c < 2; ++c)                                            \
            _Pragma("unroll")                                                  \
            for (int cs = 0; cs < 2; ++cs)                                     \
                _Pragma("unroll")                                              \
                for (int ps = 0; ps < 2; ++ps)                                 \
                    acc[c][cs][ps] = MFMA16(aL[c][cs][1], bh[ps][1], acc[c][cs][ps]); \
        _Pragma("unroll")                                                      \
        for (int c = 0; c < 2; ++c)                                            \
            _Pragma("unroll")                                                  \
            for (int cs = 0; cs < 2; ++cs)                                     \
                _Pragma("unroll")                                              \
                for (int ps = 0; ps < 2; ++ps)                                 \
                    acc[c][cs][ps] = MFMA16(aH[c][cs][0], bl[ps][0], acc[c][cs][ps]); \
        _Pragma("unroll")                                                      \
        for (int c = 0; c < 2; ++c)                                            \
            _Pragma("unroll")                                                  \
            for (int cs = 0; cs < 2; ++cs)                                     \
                _Pragma("unroll")                                              \
                for (int ps = 0; ps < 2; ++ps)                                 \
                    acc[c][cs][ps] = MFMA16(aH[c][cs][1], bl[ps][1], acc[c][cs][ps]); \
        __builtin_amdgcn_s_setprio(0);                                         \
        _Pragma("unroll")                                                      \
        for (int ps = 0; ps < 2; ++ps) {                                       \
            float v0 = acc[0][0][ps][0], v1 = acc[0][0][ps][1];                \
            float v2 = acc[0][0][ps][2], v3 = acc[0][0][ps][3];                \
            float v4 = acc[0][1][ps][0], v5 = acc[0][1][ps][1];                \
            float v6 = acc[0][1][ps][2], v7 = acc[0][1][ps][3];                \
            float v8 = acc[1][0][ps][0], v9 = acc[1][0][ps][1];                \
            float v10 = acc[1][0][ps][2], v11 = acc[1][0][ps][3];              \
            float v12 = acc[1][1][ps][0], v13 = acc[1][1][ps][1];              \
            float v14 = acc[1][1][ps][2], v15 = acc[1][1][ps][3];              \
            float a0 = fminf(v0, v1),   a1 = fminf(v2, v3);                    \
            float a2 = fminf(v4, v5),   a3 = fminf(v6, v7);                    \
            float a4 = fminf(v8, v9),   a5 = fminf(v10, v11);                  \
            float a6 = fminf(v12, v13), a7 = fminf(v14, v15);                  \
            float b0 = fminf(a0, a1), b1 = fminf(a2, a3);                      \
            float b2 = fminf(a4, a5), b3 = fminf(a6, a7);                      \
            float c0 = fminf(b0, b1), c1 = fminf(b2, b3);                      \
            float m  = fminf(c0, c1);                                          \
            bool  L3 = (m == c0);                                              \
            float bL = L3 ? b0 : b2;                                           \
            bool  L2 = (m == bL);                                              \
            float aLv = L3 ? (L2 ? a0 : a2) : (L2 ? a4 : a6);                  \
            bool  L1 = (m == aLv);                                             \
            float vE = L3 ? (L2 ? (L1 ? v0 : v2) : (L1 ? v4 : v6))             \
                          : (L2 ? (L1 ? v8 : v10) : (L1 ? v12 : v14));         \
            bool  L0 = (m == vE);                                              \
            int ji = (L3 ? 0 : 8) | (L2 ? 0 : 4) | (L1 ? 0 : 2) | (L0 ? 0 : 1); \
            int ci = wb + (ji >> 3) * 32 + ((ji >> 2) & 1) * 16 + grp4 + (ji & 3); \
            float bdp = m; int bip = ci;                                       \
            float od = __shfl_xor(bdp, 16); int oi = __shfl_xor(bip, 16);      \
            if (od < bdp || (od == bdp && oi < bip)) { bdp = od; bip = oi; }   \
            od = __shfl_xor(bdp, 32); oi = __shfl_xor(bip, 32);                \
            if (od < bdp || (od == bdp && oi < bip)) { bdp = od; bip = oi; }   \
            if (grp == 0) {                                                    \
                partd[buf_][wave][ps * 16 + l15] = bdp;                        \
                parti[buf_][wave][ps * 16 + l15] = (float)bip;                 \
            }                                                                  \
        }                                                                      \
    }

// Combine tile T: 32 threads scan the 8 wave-partials (ascending w + explicit
// tie-break = global first-index), add exact x2, write idx/dist.
#define COMBINE(T)                                                             \
    {                                                                          \
        if (tid < 32) {                                                        \
            int buf_ = (T) & 1;                                                \
            int p = tid;                                                       \
            float bdv = partd[buf_][0][p];                                     \
            float biv = parti[buf_][0][p];                                     \
            _Pragma("unroll")                                                  \
            for (int w = 1; w < 8; ++w) {                                      \
                float od = partd[buf_][w][p], oi = parti[buf_][w][p];          \
                bool imp = (od < bdv) || (od == bdv && oi < biv);              \
                bdv = imp ? od : bdv;                                          \
                biv = imp ? oi : biv;                                          \
            }                                                                  \
            float x2v = x2buf[(T) % 3][p];                                     \
            size_t pp = (size_t)(T) * 32 + p;                                  \
            out_idx[pp]  = biv;                                                \
            out_dist[pp] = sqrtf(fmaxf(bdv + x2v, 0.f));                       \
        }                                                                      \
    }

// ---- main kernel: CENTROIDS IN REGISTERS, POINTS STREAM. 8 waves/block;
// wave w permanently holds cents [w*64,(w+1)*64) (A hi+lo, 64 regs, loaded
// ONCE -> the ~39us/CU A-redelivery term from R8-R20 is eliminated).
__global__ __launch_bounds__(512, 2)
void kmeans_mfma(const float* __restrict__ X,
                 const _Float16* __restrict__ cbf,
                 const float* __restrict__ c2,
                 float* __restrict__ out_idx,
                 float* __restrict__ out_dist) {
    __shared__ _Float16 Bbuf[2][4096];    // 2 x 8 KB point-tile fragments
    __shared__ float partd[2][8][32];     // per-wave partial min dist
    __shared__ float parti[2][8][32];     // per-wave partial argmin
    __shared__ float x2buf[3][32];        // ||x||^2 (staged ahead -> mod 3)

    int tid  = threadIdx.x;
    int wave = tid >> 6;
    int lane = tid & 63;
    int l15  = lane & 15;
    int grp  = lane >> 4;
    int grp4 = grp * 4;
    int wb   = wave * 64;                 // this wave's centroid base

    // ---- load this wave's A-fragments (chunks 2w, 2w+1) + c2 C-in, ONCE
    half8 aH[2][2][2], aL[2][2][2];       // [chunk][cs][ks]
    f32x4 q[2][2];
#pragma unroll
    for (int c = 0; c < 2; ++c) {
#pragma unroll
        for (int cs = 0; cs < 2; ++cs) {
#pragma unroll
            for (int ks = 0; ks < 2; ++ks) {
                size_t bh_ = ((((size_t)(2 * wave + c) * 2 + 0) * 2 + cs) * 2 + ks) * 512 + (size_t)lane * 8;
                size_t bl_ = ((((size_t)(2 * wave + c) * 2 + 1) * 2 + cs) * 2 + ks) * 512 + (size_t)lane * 8;
                aH[c][cs][ks] = *(const half8*)(cbf + bh_);
                aL[c][cs][ks] = *(const half8*)(cbf + bl_);
            }
            q[c][cs] = *(const f32x4*)(c2 + wb + c * 32 + cs * 16 + grp4);
        }
    }

    int t0 = blockIdx.x * TPB_TILES;
    int t1 = t0 + TPB_TILES; if (t1 > N_TILES) t1 = N_TILES;

    STAGE(t0)
    __syncthreads();

#pragma unroll 1
    for (int t = t0; t < t1; ++t) {
        if (t + 1 < t1) STAGE(t + 1)
        COMPUTE(t)
        if (t > t0) COMBINE(t - 1)
        __syncthreads();
    }
    COMBINE(t1 - 1)
}

extern "C" void kernel_launch(void* const* d_in, const int* in_sizes, int n_in,
                              void* d_out, int out_size, void* d_ws, size_t ws_size,
                              hipStream_t stream) {
    const float* X  = (const float*)d_in[0];
    const float* cb = (const float*)d_in[1];
    float* out      = (float*)d_out;

    // workspace: fragment-ordered codebook 128KB | c2 2KB
    _Float16* cbf = (_Float16*)d_ws;
    float*    c2  = (float*)(cbf + (size_t)K_CENT * W_DIM * 2);

    hipLaunchKernelGGL(cvt_kernel, dim3((K_CENT * 8 + 255) / 256), dim3(256), 0, stream, cb, cbf);
    hipLaunchKernelGGL(c2_kernel, dim3((K_CENT + 255) / 256), dim3(256), 0, stream, cb, c2);

    hipLaunchKernelGGL(kmeans_mfma, dim3(N_BLOCKS), dim3(512), 0, stream,
                       X, cbf, c2, out, out + N_POINTS);
}

// Round 22
// 146.183 us; speedup vs baseline: 1.0408x; 1.0408x over previous
//
#include <hip/hip_runtime.h>

#define N_POINTS  500000
#define K_CENT    512
#define W_DIM     64
#define N_TILES   (N_POINTS / 32)              // 15625 exact 32-point tiles
#define TPB_TILES 21
#define N_BLOCKS  ((N_TILES + TPB_TILES - 1) / TPB_TILES)   // 745 -> 2-3 blk/CU

typedef _Float16 half8 __attribute__((ext_vector_type(8)));
typedef float    f32x4 __attribute__((ext_vector_type(4)));

// ---- pre-kernel 1 (verbatim R20): codebook -> fragment-ordered f16 hi/lo of
// w=-2c. Layout [t:16][pl:2][cs:2][ks:2][lane:64][j:8]; cent c = t*32+cs*16+
// (l&15), dim d = ks*32+(l>>4)*8+j; lo = unscaled residual (REQUIRED, R19).
__global__ void cvt_kernel(const float* __restrict__ cb,
                           _Float16* __restrict__ cbf) {
    int id = blockIdx.x * 256 + threadIdx.x;           // 4096 ids
    if (id >= K_CENT * 8) return;
    int c = id >> 3, o = (id & 7) * 8;
    int t = c >> 5, csub = (c >> 4) & 1, r = c & 15;
    int kstep = o >> 5, grp = (o >> 3) & 3;
    int lane = grp * 16 + r;
    const float* src = cb + (size_t)c * W_DIM + o;
    half8 h, l;
#pragma unroll
    for (int j = 0; j < 8; ++j) {
        float w = -2.0f * src[j];
        _Float16 hh = (_Float16)w;                     // RNE
        h[j] = hh;
        l[j] = (_Float16)(w - (float)hh);
    }
    size_t bh = ((((size_t)t * 2 + 0) * 2 + csub) * 2 + kstep) * 512 + (size_t)lane * 8;
    size_t bl = ((((size_t)t * 2 + 1) * 2 + csub) * 2 + kstep) * 512 + (size_t)lane * 8;
    *(half8*)(cbf + bh) = h;
    *(half8*)(cbf + bl) = l;
}

// ---- pre-kernel 2 (verbatim): c2 in double
__global__ void c2_kernel(const float* __restrict__ cb, float* __restrict__ c2) {
    int c = blockIdx.x * 256 + threadIdx.x;
    if (c >= K_CENT) return;
    const float4* row = (const float4*)(cb + (size_t)c * W_DIM);
    double s = 0.0;
#pragma unroll
    for (int j = 0; j < W_DIM / 4; ++j) {
        float4 v = row[j];
        s += (double)v.x * v.x + (double)v.y * v.y + (double)v.z * v.z + (double)v.w * v.w;
    }
    c2[c] = (float)s;
}

#define MFMA16(A, B, C) __builtin_amdgcn_mfma_f32_16x16x32_f16(A, B, C, 0, 0, 0)

// Stage tile T (waves 0-3 only): wave w = (ps = w>>1, ks = w&1); lane =
// (gd = lane>>4, lp = lane&15) -> point p = ps*16+lp, dims ks*32+gd*8..+7.
// Loads one full 128B line per point (X read ONCE), writes hi/lo half8 at
// seg*1024 + lane*16 bytes -> LINEAR in lane (conflict-free, R14-R20 pattern).
// x2 partial (8 dims, fixed-order fmaf) -> x2part[T%3][ks*4+gd][p].
#define STAGE(T)                                                               \
    if (wave < 4) {                                                            \
        int ps_ = wave >> 1, ks_ = wave & 1;                                   \
        int gd_ = lane >> 4, lp_ = lane & 15;                                  \
        int p_  = ps_ * 16 + lp_;                                              \
        const float* xs = X + ((size_t)(T) * 32 + p_) * W_DIM + ks_ * 32 + gd_ * 8; \
        float4 f0 = *(const float4*)xs, f1 = *(const float4*)(xs + 4);         \
        float fa[8] = {f0.x, f0.y, f0.z, f0.w, f1.x, f1.y, f1.z, f1.w};        \
        half8 hi, lo; float x2p = 0.f;                                         \
        _Pragma("unroll")                                                      \
        for (int j = 0; j < 8; ++j) {                                          \
            _Float16 hh = (_Float16)fa[j];                                     \
            hi[j] = hh;                                                        \
            lo[j] = (_Float16)(fa[j] - (float)hh);                             \
            x2p = fmaf(fa[j], fa[j], x2p);                                     \
        }                                                                      \
        int sh = ps_ * 4 + ks_;                                                \
        *(half8*)&Bbuf[(T) & 1][(sh + 0) * 512 + lane * 8] = hi;               \
        *(half8*)&Bbuf[(T) & 1][(sh + 2) * 512 + lane * 8] = lo;               \
        x2part[(T) % 3][ks_ * 4 + gd_][p_] = x2p;                              \
    }

// Compute tile T: 8 x ds_read_b128 at seg*1024 + lane*16 (linear, conflict-
// free), 48 MFMAs = 8 chains (c,cs,ps) x 6-deep 3-term, C-in = q (c2, regs).
// Per-wave partial argmin over its 64 cents -> part[T&1][wave].
#define COMPUTE(T)                                                             \
    {                                                                          \
        int buf_ = (T) & 1;                                                    \
        half8 bh[2][2], bl[2][2];                                              \
        _Pragma("unroll")                                                      \
        for (int ps = 0; ps < 2; ++ps)                                         \
            _Pragma("unroll")                                                  \
            for (int ks = 0; ks < 2; ++ks) {                                   \
                bh[ps][ks] = *(const half8*)&Bbuf[buf_][(ps * 4 + 0 + ks) * 512 + lane * 8]; \
                bl[ps][ks] = *(const half8*)&Bbuf[buf_][(ps * 4 + 2 + ks) * 512 + lane * 8]; \
            }                                                                  \
        f32x4 acc[2][2][2];                                                    \
        __builtin_amdgcn_s_setprio(1);                                         \
        _Pragma("unroll")                                                      \
        for (int c = 0; c < 2; ++c)                                            \
            _Pragma("unroll")                                                  \
            for (int cs = 0; cs < 2; ++cs)                                     \
                _Pragma("unroll")                                              \
                for (int ps = 0; ps < 2; ++ps)                                 \
                    acc[c][cs][ps] = MFMA16(aH[c][cs][0], bh[ps][0], q[c][cs]); \
        _Pragma("unroll")                                                      \
        for (int c = 0; c < 2; ++c)                                            \
            _Pragma("unroll")                                                  \
            for (int cs = 0; cs < 2; ++cs)                                     \
                _Pragma("unroll")                                              \
                for (int ps = 0; ps < 2; ++ps)                                 \
                    acc[c][cs][ps] = MFMA16(aH[c][cs][1], bh[ps][1], acc[c][cs][ps]); \
        _Pragma("unroll")                                                      \
        for (int c = 0; c < 2; ++c)                                            \
            _Pragma("unroll")                                                  \
            for (int cs = 0; cs < 2; ++cs)                                     \
                _Pragma("unroll")                                              \
                for (int ps = 0; ps < 2; ++ps)                                 \
                    acc[c][cs][ps] = MFMA16(aL[c][cs][0], bh[ps][0], acc[c][cs][ps]); \
        _Pragma("unroll")                                                      \
        for (int c = 0; c < 2; ++c)                                            \
            _Pragma("unroll")                                                  \
            for (int cs = 0; cs < 2; ++cs)                                     \
                _Pragma("unroll")                                              \
                for (int ps = 0; ps < 2; ++ps)                                 \
                    acc[c][cs][ps] = MFMA16(aL[c][cs][1], bh[ps][1], acc[c][cs][ps]); \
        _Pragma("unroll")                                                      \
        for (int c = 0; c < 2; ++c)                                            \
            _Pragma("unroll")                                                  \
            for (int cs = 0; cs < 2; ++cs)                                     \
                _Pragma("unroll")                                              \
                for (int ps = 0; ps < 2; ++ps)                                 \
                    acc[c][cs][ps] = MFMA16(aH[c][cs][0], bl[ps][0], acc[c][cs][ps]); \
        _Pragma("unroll")                                                      \
        for (int c = 0; c < 2; ++c)                                            \
            _Pragma("unroll")                                                  \
            for (int cs = 0; cs < 2; ++cs)                                     \
                _Pragma("unroll")                                              \
                for (int ps = 0; ps < 2; ++ps)                                 \
                    acc[c][cs][ps] = MFMA16(aH[c][cs][1], bl[ps][1], acc[c][cs][ps]); \
        __builtin_amdgcn_s_setprio(0);                                         \
        _Pragma("unroll")                                                      \
        for (int ps = 0; ps < 2; ++ps) {                                       \
            float v0 = acc[0][0][ps][0], v1 = acc[0][0][ps][1];                \
            float v2 = acc[0][0][ps][2], v3 = acc[0][0][ps][3];                \
            float v4 = acc[0][1][ps][0], v5 = acc[0][1][ps][1];                \
            float v6 = acc[0][1][ps][2], v7 = acc[0][1][ps][3];                \
            float v8 = acc[1][0][ps][0], v9 = acc[1][0][ps][1];                \
            float v10 = acc[1][0][ps][2], v11 = acc[1][0][ps][3];              \
            float v12 = acc[1][1][ps][0], v13 = acc[1][1][ps][1];              \
            float v14 = acc[1][1][ps][2], v15 = acc[1][1][ps][3];              \
            float a0 = fminf(v0, v1),   a1 = fminf(v2, v3);                    \
            float a2 = fminf(v4, v5),   a3 = fminf(v6, v7);                    \
            float a4 = fminf(v8, v9),   a5 = fminf(v10, v11);                  \
            float a6 = fminf(v12, v13), a7 = fminf(v14, v15);                  \
            float b0 = fminf(a0, a1), b1 = fminf(a2, a3);                      \
            float b2 = fminf(a4, a5), b3 = fminf(a6, a7);                      \
            float c0 = fminf(b0, b1), c1 = fminf(b2, b3);                      \
            float m  = fminf(c0, c1);                                          \
            bool  L3 = (m == c0);                                              \
            float bL = L3 ? b0 : b2;                                           \
            bool  L2 = (m == bL);                                              \
            float aLv = L3 ? (L2 ? a0 : a2) : (L2 ? a4 : a6);                  \
            bool  L1 = (m == aLv);                                             \
            float vE = L3 ? (L2 ? (L1 ? v0 : v2) : (L1 ? v4 : v6))             \
                          : (L2 ? (L1 ? v8 : v10) : (L1 ? v12 : v14));         \
            bool  L0 = (m == vE);                                              \
            int ji = (L3 ? 0 : 8) | (L2 ? 0 : 4) | (L1 ? 0 : 2) | (L0 ? 0 : 1); \
            int ci = wb + (ji >> 3) * 32 + ((ji >> 2) & 1) * 16 + grp4 + (ji & 3); \
            float bdp = m; int bip = ci;                                       \
            float od = __shfl_xor(bdp, 16); int oi = __shfl_xor(bip, 16);      \
            if (od < bdp || (od == bdp && oi < bip)) { bdp = od; bip = oi; }   \
            od = __shfl_xor(bdp, 32); oi = __shfl_xor(bip, 32);                \
            if (od < bdp || (od == bdp && oi < bip)) { bdp = od; bip = oi; }   \
            if (grp == 0) {                                                    \
                partd[buf_][wave][ps * 16 + l15] = bdp;                        \
                parti[buf_][wave][ps * 16 + l15] = (float)bip;                 \
            }                                                                  \
        }                                                                      \
    }

// Combine tile T: 32 threads; merge 8 wave-partials ascending (explicit
// tie-break = global first-index); x2 = fixed-order sum of 8 partials.
#define COMBINE(T)                                                             \
    {                                                                          \
        if (tid < 32) {                                                        \
            int buf_ = (T) & 1, b3_ = (T) % 3;                                 \
            int p = tid;                                                       \
            float bdv = partd[buf_][0][p];                                     \
            float biv = parti[buf_][0][p];                                     \
            _Pragma("unroll")                                                  \
            for (int w = 1; w < 8; ++w) {                                      \
                float od = partd[buf_][w][p], oi = parti[buf_][w][p];          \
                bool imp = (od < bdv) || (od == bdv && oi < biv);              \
                bdv = imp ? od : bdv;                                          \
                biv = imp ? oi : biv;                                          \
            }                                                                  \
            float x2v = x2part[b3_][0][p];                                     \
            _Pragma("unroll")                                                  \
            for (int w = 1; w < 8; ++w) x2v += x2part[b3_][w][p];              \
            size_t pp = (size_t)(T) * 32 + p;                                  \
            out_idx[pp]  = biv;                                                \
            out_dist[pp] = sqrtf(fmaxf(bdv + x2v, 0.f));                       \
        }                                                                      \
    }

// ---- main kernel: CENTROIDS IN REGISTERS, POINTS STREAM. 8 waves/block;
// wave w holds cents [w*64,(w+1)*64) loaded ONCE (A-redelivery eliminated).
// R22 fixes vs R21: conflict-free linear STAGE writes + 745 blocks (2-3/CU).
__global__ __launch_bounds__(512, 2)
void kmeans_mfma(const float* __restrict__ X,
                 const _Float16* __restrict__ cbf,
                 const float* __restrict__ c2,
                 float* __restrict__ out_idx,
                 float* __restrict__ out_dist) {
    __shared__ _Float16 Bbuf[2][4096];    // 2 x 8 KB point-tile fragments
    __shared__ float partd[2][8][32];     // per-wave partial min dist
    __shared__ float parti[2][8][32];     // per-wave partial argmin
    __shared__ float x2part[3][8][32];    // ||x||^2 partials (staged ahead)

    int tid  = threadIdx.x;
    int wave = tid >> 6;
    int lane = tid & 63;
    int l15  = lane & 15;
    int grp  = lane >> 4;
    int grp4 = grp * 4;
    int wb   = wave * 64;                 // this wave's centroid base

    // ---- load this wave's A-fragments (chunks 2w, 2w+1) + c2 C-in, ONCE
    half8 aH[2][2][2], aL[2][2][2];       // [chunk][cs][ks]
    f32x4 q[2][2];
#pragma unroll
    for (int c = 0; c < 2; ++c) {
#pragma unroll
        for (int cs = 0; cs < 2; ++cs) {
#pragma unroll
            for (int ks = 0; ks < 2; ++ks) {
                size_t bh_ = ((((size_t)(2 * wave + c) * 2 + 0) * 2 + cs) * 2 + ks) * 512 + (size_t)lane * 8;
                size_t bl_ = ((((size_t)(2 * wave + c) * 2 + 1) * 2 + cs) * 2 + ks) * 512 + (size_t)lane * 8;
                aH[c][cs][ks] = *(const half8*)(cbf + bh_);
                aL[c][cs][ks] = *(const half8*)(cbf + bl_);
            }
            q[c][cs] = *(const f32x4*)(c2 + wb + c * 32 + cs * 16 + grp4);
        }
    }

    int t0 = blockIdx.x * TPB_TILES;
    int t1 = t0 + TPB_TILES; if (t1 > N_TILES) t1 = N_TILES;

    STAGE(t0)
    __syncthreads();

#pragma unroll 1
    for (int t = t0; t < t1; ++t) {
        if (t + 1 < t1) STAGE(t + 1)
        COMPUTE(t)
        if (t > t0) COMBINE(t - 1)
        __syncthreads();
    }
    COMBINE(t1 - 1)
}

extern "C" void kernel_launch(void* const* d_in, const int* in_sizes, int n_in,
                              void* d_out, int out_size, void* d_ws, size_t ws_size,
                              hipStream_t stream) {
    const float* X  = (const float*)d_in[0];
    const float* cb = (const float*)d_in[1];
    float* out      = (float*)d_out;

    // workspace: fragment-ordered codebook 128KB | c2 2KB
    _Float16* cbf = (_Float16*)d_ws;
    float*    c2  = (float*)(cbf + (size_t)K_CENT * W_DIM * 2);

    hipLaunchKernelGGL(cvt_kernel, dim3((K_CENT * 8 + 255) / 256), dim3(256), 0, stream, cb, cbf);
    hipLaunchKernelGGL(c2_kernel, dim3((K_CENT + 255) / 256), dim3(256), 0, stream, cb, c2);

    hipLaunchKernelGGL(kmeans_mfma, dim3(N_BLOCKS), dim3(512), 0, stream,
                       X, cbf, c2, out, out + N_POINTS);
}